// Round 10
// baseline (235.075 us; speedup 1.0000x reference)
//
#include <hip/hip_runtime.h>
#include <hip/hip_cooperative_groups.h>

namespace cg = cooperative_groups;

#define N_NODES 50000
#define N_EDGES 800000
#define D 256
#define SCAN_BLOCKS 49      // ceil(50000/1024)
#define CSR_BLOCKS 256      // full-machine coop grid (1 block/CU guaranteed)
#define GEMM_BLOCKS 391     // ceil(50000/128), 128x256 tile per block
#define DEG_BLOCKS 1563     // ceil(800000/512)

typedef unsigned short bf16_t;
typedef __attribute__((ext_vector_type(8))) short short8;
typedef __attribute__((ext_vector_type(4))) float f32x4;

__device__ inline float b2f(bf16_t u) {
    union { float f; unsigned v; } t; t.v = ((unsigned)u) << 16; return t.f;
}
__device__ inline bf16_t f2b(float f) {
    union { float f; unsigned v; } t; t.f = f;
    unsigned u = t.v;
    return (bf16_t)((u + 0x7FFFu + ((u >> 16) & 1u)) >> 16);   // RNE
}
__device__ inline unsigned cvt_pk_bf16(float lo, float hi) {
    unsigned r;
    asm("v_cvt_pk_bf16_f32 %0, %1, %2" : "=v"(r) : "v"(lo), "v"(hi));
    return r;
}
__device__ inline short8 cvt8(float4 a, float4 b) {
    union { short8 s; unsigned u[4]; } t;
    t.u[0] = cvt_pk_bf16(a.x, a.y);
    t.u[1] = cvt_pk_bf16(a.z, a.w);
    t.u[2] = cvt_pk_bf16(b.x, b.y);
    t.u[3] = cvt_pk_bf16(b.z, b.w);
    return t.s;
}

// ---------------------------------------------------------------------------
// K1: fused {MFMA GEMM | degree histogram}.
//    GEMM (blocks [0, GEMM_BLOCKS)): h = x @ W^T, 128x256 tile (x read ONCE),
//    BK=32, 512 thr = 8 waves (2 wr x 4 wc), wave 64x64 = 4x4 frags of
//    16x16x32. A (x) and B (W, L2-hot) reg-staged fp32 + fused cvt_pk -> LDS.
//    D[i][j]: col = l&15, row = (l>>4)*4 + reg        (m89-verified)
//    DEG (remaining blocks): atomic histogram over edge dst.
// ---------------------------------------------------------------------------
__global__ __launch_bounds__(512) void k1_kernel(const float* __restrict__ x,
                                                 const float* __restrict__ W,
                                                 bf16_t* __restrict__ h,
                                                 const int* __restrict__ ei,
                                                 int* __restrict__ deg) {
    __shared__ __align__(16) bf16_t As[128 * 32];
    __shared__ __align__(16) bf16_t Bs[256 * 32];

    const int tid = threadIdx.x;

    if (blockIdx.x >= GEMM_BLOCKS) {
        // ---- degree histogram ----
        int e = (blockIdx.x - GEMM_BLOCKS) * 512 + tid;
        if (e < N_EDGES) {
            int d = ei[N_EDGES + e];
            if ((unsigned)d < (unsigned)N_NODES) atomicAdd(&deg[d], 1);
        }
        return;
    }

    // ---- GEMM tile ----
    const int wid  = tid >> 6;   // 0..7
    const int lane = tid & 63;
    const int wr = wid >> 2;     // 0..1
    const int wc = wid & 3;      // 0..3
    const int row0 = blockIdx.x * 128;
    const int lr = lane & 15;
    const int lk = (lane >> 4) * 8;

    // staging maps: thread t -> row = t>>2, quarter q = t&3 (k-offset q*8)
    const int srow = tid >> 2;   // 0..127
    const int sq   = tid & 3;
    int sr = row0 + srow;
    if (sr >= N_NODES) sr = N_NODES - 1;   // clamp; stores guarded
    const float* agp = &x[(size_t)sr * D + sq * 8];
    bf16_t* alp = &As[srow * 32 + sq * 8];

    f32x4 acc[4][4] = {};

    for (int k0 = 0; k0 < D; k0 += 32) {
        {   // A: 128x32
            const float4* p = reinterpret_cast<const float4*>(&agp[k0]);
            float4 v0 = p[0], v1 = p[1];
            *reinterpret_cast<short8*>(alp) = cvt8(v0, v1);
        }
#pragma unroll
        for (int j = 0; j < 2; j++) {   // B: 256x32, two passes
            int brow = (j * 512 + tid) >> 2;
            const float4* q = reinterpret_cast<const float4*>(&W[(size_t)brow * D + k0 + sq * 8]);
            float4 w0 = q[0], w1 = q[1];
            *reinterpret_cast<short8*>(&Bs[brow * 32 + sq * 8]) = cvt8(w0, w1);
        }
        __syncthreads();

        short8 a[4], b[4];
#pragma unroll
        for (int m = 0; m < 4; m++)
            a[m] = *reinterpret_cast<const short8*>(&As[(wr * 64 + m * 16 + lr) * 32 + lk]);
#pragma unroll
        for (int n = 0; n < 4; n++)
            b[n] = *reinterpret_cast<const short8*>(&Bs[(wc * 64 + n * 16 + lr) * 32 + lk]);
#pragma unroll
        for (int m = 0; m < 4; m++)
#pragma unroll
            for (int n = 0; n < 4; n++)
                acc[m][n] = __builtin_amdgcn_mfma_f32_16x16x32_bf16(a[m], b[n], acc[m][n], 0, 0, 0);
        __syncthreads();
    }

#pragma unroll
    for (int m = 0; m < 4; m++) {
        int rbase = row0 + wr * 64 + m * 16 + (lane >> 4) * 4;
#pragma unroll
        for (int j = 0; j < 4; j++) {
            int rr = rbase + j;
            if (rr < N_NODES) {
#pragma unroll
                for (int n = 0; n < 4; n++)
                    h[(size_t)rr * D + wc * 64 + n * 16 + lr] = f2b(acc[m][n][j]);
            }
        }
    }
}

// ---------------------------------------------------------------------------
// K2 (cooperative, CSR_BLOCKS blocks): scan phases on blocks [0,49); fill on
//    the FULL grid (the R9 mistake was running fill on 49 blocks = 7% occ).
// ---------------------------------------------------------------------------
__global__ __launch_bounds__(1024) void csr_kernel(const int* __restrict__ ei,
                                                   const int* __restrict__ deg,
                                                   int* __restrict__ cursor,
                                                   int* __restrict__ blk_sum,
                                                   int* __restrict__ row_ptr,
                                                   float* __restrict__ dinv,
                                                   int* __restrict__ csr_src) {
    cg::grid_group grid = cg::this_grid();
    const int tid  = threadIdx.x;
    const int bid  = blockIdx.x;
    const int lane = tid & 63;
    const int wvi  = tid >> 6;  // 0..15
    __shared__ int wsum[16];
    __shared__ int sh_off, sh_tot;

    // ---- phase A (blocks < SCAN_BLOCKS): local exclusive scan -> cursor, blk_sum
    if (bid < SCAN_BLOCKS) {
        int i = bid * 1024 + tid;
        int v = (i < N_NODES) ? deg[i] : 0;
        int s = v;
#pragma unroll
        for (int off = 1; off < 64; off <<= 1) {
            int t = __shfl_up(s, off, 64);
            if (lane >= off) s += t;
        }
        if (lane == 63) wsum[wvi] = s;
        __syncthreads();
        if (tid < 16) {
            int ws = wsum[tid];
            int t0 = ws;
#pragma unroll
            for (int off = 1; off < 16; off <<= 1) {
                int t = __shfl_up(t0, off, 64);
                if ((int)tid >= off) t0 += t;
            }
            wsum[tid] = t0 - ws;
            if (tid == 15) blk_sum[bid] = t0;
        }
        __syncthreads();
        if (i < N_NODES) cursor[i] = wsum[wvi] + s - v;
    }

    grid.sync();

    // ---- phase B (blocks < SCAN_BLOCKS): apply block offsets
    if (bid < SCAN_BLOCKS) {
        int i = bid * 1024 + tid;
        if (tid < 64) {
            int l = tid;
            int v = (l < SCAN_BLOCKS) ? blk_sum[l] : 0;
            int s = v;
#pragma unroll
            for (int off = 1; off < 64; off <<= 1) {
                int t = __shfl_up(s, off, 64);
                if (l >= off) s += t;
            }
            if (l == bid)             sh_off = s - v;
            if (l == SCAN_BLOCKS - 1) sh_tot = s;
        }
        __syncthreads();
        if (i < N_NODES) {
            int rp = cursor[i] + sh_off;
            row_ptr[i] = rp;
            cursor[i]  = rp;
            dinv[i] = rsqrtf((float)(deg[i] + 1));
        }
        if (bid == SCAN_BLOCKS - 1 && tid == 0) row_ptr[N_NODES] = sh_tot;
    }

    grid.sync();

    // ---- phase C (ALL blocks): bucket fill, grid-stride ~3 edges/thread
    const int NT = CSR_BLOCKS * 1024;
    for (int e = bid * 1024 + tid; e < N_EDGES; e += NT) {
        int s = ei[e];
        int d = ei[N_EDGES + e];
        if ((unsigned)d < (unsigned)N_NODES) {
            int pos = atomicAdd(&cursor[d], 1);
            csr_src[pos] = s;
        }
    }
}

// ---------------------------------------------------------------------------
// K3: gather-reduce + self-loop + bias + alpha blend. One wave per dst node.
//    h is bf16; lane owns 4 columns (8B loads). Unroll-8 for MLP.
// ---------------------------------------------------------------------------
__global__ __launch_bounds__(256) void gather_kernel(const int* __restrict__ row_ptr,
                                                     const int* __restrict__ csr_src,
                                                     const float* __restrict__ dinv,
                                                     const bf16_t* __restrict__ h,
                                                     const float* __restrict__ x,
                                                     const float* __restrict__ b,
                                                     const float* __restrict__ alpha,
                                                     float* __restrict__ out) {
    int n    = blockIdx.x * 4 + (threadIdx.x >> 6);
    int lane = threadIdx.x & 63;
    if (n >= N_NODES) return;

    const int beg = row_ptr[n];
    const int end = row_ptr[n + 1];
    const float dn = dinv[n];
    const bf16_t* hl = h + (size_t)lane * 4;

    float ax = 0.f, ay = 0.f, az = 0.f, aw = 0.f;
    int k = beg;
    for (; k + 7 < end; k += 8) {
        int s0 = csr_src[k],     s1 = csr_src[k + 1], s2 = csr_src[k + 2], s3 = csr_src[k + 3];
        int s4 = csr_src[k + 4], s5 = csr_src[k + 5], s6 = csr_src[k + 6], s7 = csr_src[k + 7];
        float n0 = dinv[s0] * dn, n1 = dinv[s1] * dn, n2 = dinv[s2] * dn, n3 = dinv[s3] * dn;
        float n4 = dinv[s4] * dn, n5 = dinv[s5] * dn, n6 = dinv[s6] * dn, n7 = dinv[s7] * dn;
        ushort4 h0 = *reinterpret_cast<const ushort4*>(&hl[(size_t)s0 * D]);
        ushort4 h1 = *reinterpret_cast<const ushort4*>(&hl[(size_t)s1 * D]);
        ushort4 h2 = *reinterpret_cast<const ushort4*>(&hl[(size_t)s2 * D]);
        ushort4 h3 = *reinterpret_cast<const ushort4*>(&hl[(size_t)s3 * D]);
        ushort4 h4 = *reinterpret_cast<const ushort4*>(&hl[(size_t)s4 * D]);
        ushort4 h5 = *reinterpret_cast<const ushort4*>(&hl[(size_t)s5 * D]);
        ushort4 h6 = *reinterpret_cast<const ushort4*>(&hl[(size_t)s6 * D]);
        ushort4 h7 = *reinterpret_cast<const ushort4*>(&hl[(size_t)s7 * D]);
        ax += b2f(h0.x) * n0 + b2f(h1.x) * n1 + b2f(h2.x) * n2 + b2f(h3.x) * n3
            + b2f(h4.x) * n4 + b2f(h5.x) * n5 + b2f(h6.x) * n6 + b2f(h7.x) * n7;
        ay += b2f(h0.y) * n0 + b2f(h1.y) * n1 + b2f(h2.y) * n2 + b2f(h3.y) * n3
            + b2f(h4.y) * n4 + b2f(h5.y) * n5 + b2f(h6.y) * n6 + b2f(h7.y) * n7;
        az += b2f(h0.z) * n0 + b2f(h1.z) * n1 + b2f(h2.z) * n2 + b2f(h3.z) * n3
            + b2f(h4.z) * n4 + b2f(h5.z) * n5 + b2f(h6.z) * n6 + b2f(h7.z) * n7;
        aw += b2f(h0.w) * n0 + b2f(h1.w) * n1 + b2f(h2.w) * n2 + b2f(h3.w) * n3
            + b2f(h4.w) * n4 + b2f(h5.w) * n5 + b2f(h6.w) * n6 + b2f(h7.w) * n7;
    }
    for (; k + 3 < end; k += 4) {
        int s0 = csr_src[k], s1 = csr_src[k + 1], s2 = csr_src[k + 2], s3 = csr_src[k + 3];
        float n0 = dinv[s0] * dn, n1 = dinv[s1] * dn, n2 = dinv[s2] * dn, n3 = dinv[s3] * dn;
        ushort4 h0 = *reinterpret_cast<const ushort4*>(&hl[(size_t)s0 * D]);
        ushort4 h1 = *reinterpret_cast<const ushort4*>(&hl[(size_t)s1 * D]);
        ushort4 h2 = *reinterpret_cast<const ushort4*>(&hl[(size_t)s2 * D]);
        ushort4 h3 = *reinterpret_cast<const ushort4*>(&hl[(size_t)s3 * D]);
        ax += b2f(h0.x) * n0 + b2f(h1.x) * n1 + b2f(h2.x) * n2 + b2f(h3.x) * n3;
        ay += b2f(h0.y) * n0 + b2f(h1.y) * n1 + b2f(h2.y) * n2 + b2f(h3.y) * n3;
        az += b2f(h0.z) * n0 + b2f(h1.z) * n1 + b2f(h2.z) * n2 + b2f(h3.z) * n3;
        aw += b2f(h0.w) * n0 + b2f(h1.w) * n1 + b2f(h2.w) * n2 + b2f(h3.w) * n3;
    }
    for (; k < end; k++) {
        int s0 = csr_src[k];
        float n0 = dinv[s0] * dn;
        ushort4 h0 = *reinterpret_cast<const ushort4*>(&hl[(size_t)s0 * D]);
        ax += b2f(h0.x) * n0;
        ay += b2f(h0.y) * n0;
        az += b2f(h0.z) * n0;
        aw += b2f(h0.w) * n0;
    }

    float dv2 = dn * dn;
    float a   = alpha[0];
    ushort4 hv = *reinterpret_cast<const ushort4*>(&hl[(size_t)n * D]);
    float4  xv = *reinterpret_cast<const float4*>(&x[(size_t)n * D + lane * 4]);
    float4  bv = *reinterpret_cast<const float4*>(&b[lane * 4]);
    float4 r;
    r.x = a * xv.x + (1.0f - a) * (ax + dv2 * b2f(hv.x) + bv.x);
    r.y = a * xv.y + (1.0f - a) * (ay + dv2 * b2f(hv.y) + bv.y);
    r.z = a * xv.z + (1.0f - a) * (az + dv2 * b2f(hv.z) + bv.z);
    r.w = a * xv.w + (1.0f - a) * (aw + dv2 * b2f(hv.w) + bv.w);
    *reinterpret_cast<float4*>(&out[(size_t)n * D + lane * 4]) = r;
}

// ---------------------------------------------------------------------------
extern "C" void kernel_launch(void* const* d_in, const int* in_sizes, int n_in,
                              void* d_out, int out_size, void* d_ws, size_t ws_size,
                              hipStream_t stream) {
    const float* x     = (const float*)d_in[0];
    const int*   ei    = (const int*)d_in[1];
    const float* W     = (const float*)d_in[2];
    const float* b     = (const float*)d_in[3];
    const float* alpha = (const float*)d_in[4];
    float* out = (float*)d_out;

    char* ws = (char*)d_ws;
    const size_t HB = (size_t)N_NODES * D * 2;  // 25,600,000
    bf16_t* h      = (bf16_t*)ws;
    int*   deg     = (int*)  (ws + HB);                 // 200,000
    int*   row_ptr = (int*)  (ws + HB + 200000);        // 200,016 (N+1, padded)
    int*   cursor  = (int*)  (ws + HB + 400016);        // 200,000 (loc -> cursor)
    float* dinv    = (float*)(ws + HB + 600016);        // 200,000
    int*   blk_sum = (int*)  (ws + HB + 800016);        // 512
    int*   csr_src = (int*)  (ws + HB + 800528);        // 3,200,000

    (void)hipMemsetAsync(deg, 0, (size_t)N_NODES * 4, stream);

    k1_kernel<<<GEMM_BLOCKS + DEG_BLOCKS, 512, 0, stream>>>(x, W, h, ei, deg);

    {
        const int* ei_a = ei; const int* deg_a = deg;
        int* cursor_a = cursor; int* blk_sum_a = blk_sum;
        int* row_ptr_a = row_ptr; float* dinv_a = dinv; int* csr_a = csr_src;
        void* args[] = {&ei_a, &deg_a, &cursor_a, &blk_sum_a, &row_ptr_a, &dinv_a, &csr_a};
        (void)hipLaunchCooperativeKernel((const void*)csr_kernel, dim3(CSR_BLOCKS), dim3(1024),
                                         args, 0, stream);
    }

    gather_kernel<<<(N_NODES + 3) / 4, 256, 0, stream>>>(row_ptr, csr_src, dinv, h, x, b, alpha, out);
}

// Round 11
// 187.548 us; speedup vs baseline: 1.2534x; 1.2534x over previous
//
#include <hip/hip_runtime.h>

#define N_NODES 50000
#define N_EDGES 800000
#define D 256
#define SCAN_BLOCKS 49      // ceil(50000/1024)
#define GEMM_BLOCKS 391     // ceil(50000/128), 128x256 tile per block
#define FILL_BLOCKS 1563    // ceil(800000/512)
#define DEG_BLOCKS 1563     // ceil(800000/512)

typedef unsigned short bf16_t;
typedef __attribute__((ext_vector_type(8))) short short8;
typedef __attribute__((ext_vector_type(4))) float f32x4;

__device__ inline float b2f(bf16_t u) {
    union { float f; unsigned v; } t; t.v = ((unsigned)u) << 16; return t.f;
}
__device__ inline bf16_t f2b(float f) {
    union { float f; unsigned v; } t; t.f = f;
    unsigned u = t.v;
    return (bf16_t)((u + 0x7FFFu + ((u >> 16) & 1u)) >> 16);   // RNE
}
__device__ inline unsigned cvt_pk_bf16(float lo, float hi) {
    unsigned r;
    asm("v_cvt_pk_bf16_f32 %0, %1, %2" : "=v"(r) : "v"(lo), "v"(hi));
    return r;
}
__device__ inline short8 cvt8(float4 a, float4 b) {
    union { short8 s; unsigned u[4]; } t;
    t.u[0] = cvt_pk_bf16(a.x, a.y);
    t.u[1] = cvt_pk_bf16(a.z, a.w);
    t.u[2] = cvt_pk_bf16(b.x, b.y);
    t.u[3] = cvt_pk_bf16(b.z, b.w);
    return t.s;
}

// ---------------------------------------------------------------------------
// K1: degree histogram over edge destinations.
// ---------------------------------------------------------------------------
__global__ __launch_bounds__(512) void deg_kernel(const int* __restrict__ ei,
                                                  int* __restrict__ deg) {
    int e = blockIdx.x * 512 + threadIdx.x;
    if (e < N_EDGES) {
        int d = ei[N_EDGES + e];
        if ((unsigned)d < (unsigned)N_NODES) atomicAdd(&deg[d], 1);
    }
}

// ---------------------------------------------------------------------------
// K2: single-pass exclusive scan, decoupled aggregates (NO grid.sync).
//    Each block publishes its sum via device-scope atomicExch into agg[]
//    (pre-initialized to -1); lanes 0..47 of wave 0 spin-read predecessors'
//    aggregates in PARALLEL (atomicAdd(p,0) = coherent read), shfl-reduce.
//    All cross-block communication via device-scope atomics -> XCD-safe.
// ---------------------------------------------------------------------------
__global__ __launch_bounds__(1024) void scan_kernel(const int* __restrict__ deg,
                                                    int* __restrict__ cursor,
                                                    int* __restrict__ agg,
                                                    int* __restrict__ row_ptr,
                                                    float* __restrict__ dinv) {
    const int tid = threadIdx.x;
    const int bid = blockIdx.x;
    const int lane = tid & 63;
    const int wvi  = tid >> 6;  // 0..15
    __shared__ int wsum[16];
    __shared__ int sh_pref, sh_tot;

    int i = bid * 1024 + tid;
    int v = (i < N_NODES) ? deg[i] : 0;
    int s = v;
#pragma unroll
    for (int off = 1; off < 64; off <<= 1) {
        int t = __shfl_up(s, off, 64);
        if (lane >= off) s += t;
    }
    if (lane == 63) wsum[wvi] = s;
    __syncthreads();
    if (tid < 16) {
        int ws = wsum[tid];
        int t0 = ws;
#pragma unroll
        for (int off = 1; off < 16; off <<= 1) {
            int t = __shfl_up(t0, off, 64);
            if ((int)tid >= off) t0 += t;
        }
        wsum[tid] = t0 - ws;        // exclusive wave offset
        if (tid == 15) {
            sh_tot = t0;            // block total
            atomicExch(&agg[bid], t0);   // publish (device scope)
        }
    }
    __syncthreads();

    // parallel lookback: lane j spins on agg[j] for j < bid, then wave-reduce
    if (tid < 64) {
        int a = 0;
        if (tid < bid) {
            int val;
            do { val = atomicAdd(&agg[tid], 0); } while (val < 0);
            a = val;
        }
#pragma unroll
        for (int off = 1; off < 64; off <<= 1) a += __shfl_xor(a, off, 64);
        if (tid == 0) sh_pref = a;
    }
    __syncthreads();

    if (i < N_NODES) {
        int rp = wsum[wvi] + s - v + sh_pref;
        row_ptr[i] = rp;
        cursor[i]  = rp;
        dinv[i] = rsqrtf((float)(v + 1));
    }
    if (bid == SCAN_BLOCKS - 1 && tid == 0) row_ptr[N_NODES] = sh_pref + sh_tot;
}

// ---------------------------------------------------------------------------
// K3: fused {MFMA GEMM | CSR bucket fill} — fill rides free under the gemm.
//    GEMM (blocks [0, GEMM_BLOCKS)): h = x @ W^T, 128x256 tile (x read ONCE),
//    BK=32, 512 thr = 8 waves (2 wr x 4 wc), wave 64x64 = 4x4 frags of
//    16x16x32. A (x) and B (W, L2-hot) reg-staged fp32 + fused cvt_pk -> LDS.
//    D[i][j]: col = l&15, row = (l>>4)*4 + reg        (m89-verified)
//    FILL (remaining blocks): csr_src[atomic cursor[dst]++] = src.
// ---------------------------------------------------------------------------
__global__ __launch_bounds__(512) void gemmfill_kernel(const float* __restrict__ x,
                                                       const float* __restrict__ W,
                                                       bf16_t* __restrict__ h,
                                                       const int* __restrict__ ei,
                                                       int* __restrict__ cursor,
                                                       int* __restrict__ csr_src) {
    __shared__ __align__(16) bf16_t As[128 * 32];
    __shared__ __align__(16) bf16_t Bs[256 * 32];

    const int tid = threadIdx.x;

    if (blockIdx.x >= GEMM_BLOCKS) {
        // ---- bucket fill ----
        int e = (blockIdx.x - GEMM_BLOCKS) * 512 + tid;
        if (e < N_EDGES) {
            int s = ei[e];
            int d = ei[N_EDGES + e];
            if ((unsigned)d < (unsigned)N_NODES) {
                int pos = atomicAdd(&cursor[d], 1);
                csr_src[pos] = s;
            }
        }
        return;
    }

    // ---- GEMM tile ----
    const int wid  = tid >> 6;   // 0..7
    const int lane = tid & 63;
    const int wr = wid >> 2;     // 0..1
    const int wc = wid & 3;      // 0..3
    const int row0 = blockIdx.x * 128;
    const int lr = lane & 15;
    const int lk = (lane >> 4) * 8;

    // staging maps: thread t -> row = t>>2, quarter q = t&3 (k-offset q*8)
    const int srow = tid >> 2;   // 0..127
    const int sq   = tid & 3;
    int sr = row0 + srow;
    if (sr >= N_NODES) sr = N_NODES - 1;   // clamp; stores guarded
    const float* agp = &x[(size_t)sr * D + sq * 8];
    bf16_t* alp = &As[srow * 32 + sq * 8];

    f32x4 acc[4][4] = {};

    for (int k0 = 0; k0 < D; k0 += 32) {
        {   // A: 128x32
            const float4* p = reinterpret_cast<const float4*>(&agp[k0]);
            float4 v0 = p[0], v1 = p[1];
            *reinterpret_cast<short8*>(alp) = cvt8(v0, v1);
        }
#pragma unroll
        for (int j = 0; j < 2; j++) {   // B: 256x32, two passes
            int brow = (j * 512 + tid) >> 2;
            const float4* q = reinterpret_cast<const float4*>(&W[(size_t)brow * D + k0 + sq * 8]);
            float4 w0 = q[0], w1 = q[1];
            *reinterpret_cast<short8*>(&Bs[brow * 32 + sq * 8]) = cvt8(w0, w1);
        }
        __syncthreads();

        short8 a[4], b[4];
#pragma unroll
        for (int m = 0; m < 4; m++)
            a[m] = *reinterpret_cast<const short8*>(&As[(wr * 64 + m * 16 + lr) * 32 + lk]);
#pragma unroll
        for (int n = 0; n < 4; n++)
            b[n] = *reinterpret_cast<const short8*>(&Bs[(wc * 64 + n * 16 + lr) * 32 + lk]);
#pragma unroll
        for (int m = 0; m < 4; m++)
#pragma unroll
            for (int n = 0; n < 4; n++)
                acc[m][n] = __builtin_amdgcn_mfma_f32_16x16x32_bf16(a[m], b[n], acc[m][n], 0, 0, 0);
        __syncthreads();
    }

#pragma unroll
    for (int m = 0; m < 4; m++) {
        int rbase = row0 + wr * 64 + m * 16 + (lane >> 4) * 4;
#pragma unroll
        for (int j = 0; j < 4; j++) {
            int rr = rbase + j;
            if (rr < N_NODES) {
#pragma unroll
                for (int n = 0; n < 4; n++)
                    h[(size_t)rr * D + wc * 64 + n * 16 + lr] = f2b(acc[m][n][j]);
            }
        }
    }
}

// ---------------------------------------------------------------------------
// K4: gather-reduce + self-loop + bias + alpha blend. One wave per dst node.
//    h is bf16; lane owns 4 columns (8B loads). Unroll-8 for MLP.
// ---------------------------------------------------------------------------
__global__ __launch_bounds__(256) void gather_kernel(const int* __restrict__ row_ptr,
                                                     const int* __restrict__ csr_src,
                                                     const float* __restrict__ dinv,
                                                     const bf16_t* __restrict__ h,
                                                     const float* __restrict__ x,
                                                     const float* __restrict__ b,
                                                     const float* __restrict__ alpha,
                                                     float* __restrict__ out) {
    int n    = blockIdx.x * 4 + (threadIdx.x >> 6);
    int lane = threadIdx.x & 63;
    if (n >= N_NODES) return;

    const int beg = row_ptr[n];
    const int end = row_ptr[n + 1];
    const float dn = dinv[n];
    const bf16_t* hl = h + (size_t)lane * 4;

    float ax = 0.f, ay = 0.f, az = 0.f, aw = 0.f;
    int k = beg;
    for (; k + 7 < end; k += 8) {
        int s0 = csr_src[k],     s1 = csr_src[k + 1], s2 = csr_src[k + 2], s3 = csr_src[k + 3];
        int s4 = csr_src[k + 4], s5 = csr_src[k + 5], s6 = csr_src[k + 6], s7 = csr_src[k + 7];
        float n0 = dinv[s0] * dn, n1 = dinv[s1] * dn, n2 = dinv[s2] * dn, n3 = dinv[s3] * dn;
        float n4 = dinv[s4] * dn, n5 = dinv[s5] * dn, n6 = dinv[s6] * dn, n7 = dinv[s7] * dn;
        ushort4 h0 = *reinterpret_cast<const ushort4*>(&hl[(size_t)s0 * D]);
        ushort4 h1 = *reinterpret_cast<const ushort4*>(&hl[(size_t)s1 * D]);
        ushort4 h2 = *reinterpret_cast<const ushort4*>(&hl[(size_t)s2 * D]);
        ushort4 h3 = *reinterpret_cast<const ushort4*>(&hl[(size_t)s3 * D]);
        ushort4 h4 = *reinterpret_cast<const ushort4*>(&hl[(size_t)s4 * D]);
        ushort4 h5 = *reinterpret_cast<const ushort4*>(&hl[(size_t)s5 * D]);
        ushort4 h6 = *reinterpret_cast<const ushort4*>(&hl[(size_t)s6 * D]);
        ushort4 h7 = *reinterpret_cast<const ushort4*>(&hl[(size_t)s7 * D]);
        ax += b2f(h0.x) * n0 + b2f(h1.x) * n1 + b2f(h2.x) * n2 + b2f(h3.x) * n3
            + b2f(h4.x) * n4 + b2f(h5.x) * n5 + b2f(h6.x) * n6 + b2f(h7.x) * n7;
        ay += b2f(h0.y) * n0 + b2f(h1.y) * n1 + b2f(h2.y) * n2 + b2f(h3.y) * n3
            + b2f(h4.y) * n4 + b2f(h5.y) * n5 + b2f(h6.y) * n6 + b2f(h7.y) * n7;
        az += b2f(h0.z) * n0 + b2f(h1.z) * n1 + b2f(h2.z) * n2 + b2f(h3.z) * n3
            + b2f(h4.z) * n4 + b2f(h5.z) * n5 + b2f(h6.z) * n6 + b2f(h7.z) * n7;
        aw += b2f(h0.w) * n0 + b2f(h1.w) * n1 + b2f(h2.w) * n2 + b2f(h3.w) * n3
            + b2f(h4.w) * n4 + b2f(h5.w) * n5 + b2f(h6.w) * n6 + b2f(h7.w) * n7;
    }
    for (; k + 3 < end; k += 4) {
        int s0 = csr_src[k], s1 = csr_src[k + 1], s2 = csr_src[k + 2], s3 = csr_src[k + 3];
        float n0 = dinv[s0] * dn, n1 = dinv[s1] * dn, n2 = dinv[s2] * dn, n3 = dinv[s3] * dn;
        ushort4 h0 = *reinterpret_cast<const ushort4*>(&hl[(size_t)s0 * D]);
        ushort4 h1 = *reinterpret_cast<const ushort4*>(&hl[(size_t)s1 * D]);
        ushort4 h2 = *reinterpret_cast<const ushort4*>(&hl[(size_t)s2 * D]);
        ushort4 h3 = *reinterpret_cast<const ushort4*>(&hl[(size_t)s3 * D]);
        ax += b2f(h0.x) * n0 + b2f(h1.x) * n1 + b2f(h2.x) * n2 + b2f(h3.x) * n3;
        ay += b2f(h0.y) * n0 + b2f(h1.y) * n1 + b2f(h2.y) * n2 + b2f(h3.y) * n3;
        az += b2f(h0.z) * n0 + b2f(h1.z) * n1 + b2f(h2.z) * n2 + b2f(h3.z) * n3;
        aw += b2f(h0.w) * n0 + b2f(h1.w) * n1 + b2f(h2.w) * n2 + b2f(h3.w) * n3;
    }
    for (; k < end; k++) {
        int s0 = csr_src[k];
        float n0 = dinv[s0] * dn;
        ushort4 h0 = *reinterpret_cast<const ushort4*>(&hl[(size_t)s0 * D]);
        ax += b2f(h0.x) * n0;
        ay += b2f(h0.y) * n0;
        az += b2f(h0.z) * n0;
        aw += b2f(h0.w) * n0;
    }

    float dv2 = dn * dn;
    float a   = alpha[0];
    ushort4 hv = *reinterpret_cast<const ushort4*>(&hl[(size_t)n * D]);
    float4  xv = *reinterpret_cast<const float4*>(&x[(size_t)n * D + lane * 4]);
    float4  bv = *reinterpret_cast<const float4*>(&b[lane * 4]);
    float4 r;
    r.x = a * xv.x + (1.0f - a) * (ax + dv2 * b2f(hv.x) + bv.x);
    r.y = a * xv.y + (1.0f - a) * (ay + dv2 * b2f(hv.y) + bv.y);
    r.z = a * xv.z + (1.0f - a) * (az + dv2 * b2f(hv.z) + bv.z);
    r.w = a * xv.w + (1.0f - a) * (aw + dv2 * b2f(hv.w) + bv.w);
    *reinterpret_cast<float4*>(&out[(size_t)n * D + lane * 4]) = r;
}

// ---------------------------------------------------------------------------
extern "C" void kernel_launch(void* const* d_in, const int* in_sizes, int n_in,
                              void* d_out, int out_size, void* d_ws, size_t ws_size,
                              hipStream_t stream) {
    const float* x     = (const float*)d_in[0];
    const int*   ei    = (const int*)d_in[1];
    const float* W     = (const float*)d_in[2];
    const float* b     = (const float*)d_in[3];
    const float* alpha = (const float*)d_in[4];
    float* out = (float*)d_out;

    char* ws = (char*)d_ws;
    const size_t HB = (size_t)N_NODES * D * 2;  // 25,600,000
    bf16_t* h      = (bf16_t*)ws;
    int*   deg     = (int*)  (ws + HB);                 // 200,000
    int*   row_ptr = (int*)  (ws + HB + 200000);        // 200,016 (N+1, padded)
    int*   cursor  = (int*)  (ws + HB + 400016);        // 200,000
    float* dinv    = (float*)(ws + HB + 600016);        // 200,000
    int*   agg     = (int*)  (ws + HB + 800016);        // 256 (init 0xFF = -1)
    int*   csr_src = (int*)  (ws + HB + 800528);        // 3,200,000

    (void)hipMemsetAsync(deg, 0, (size_t)N_NODES * 4, stream);
    (void)hipMemsetAsync(agg, 0xFF, 256, stream);

    deg_kernel<<<DEG_BLOCKS, 512, 0, stream>>>(ei, deg);
    scan_kernel<<<SCAN_BLOCKS, 1024, 0, stream>>>(deg, cursor, agg, row_ptr, dinv);
    gemmfill_kernel<<<GEMM_BLOCKS + FILL_BLOCKS, 512, 0, stream>>>(x, W, h, ei, cursor, csr_src);
    gather_kernel<<<(N_NODES + 3) / 4, 256, 0, stream>>>(row_ptr, csr_src, dinv, h, x, b, alpha, out);
}